// Round 4
// baseline (859.493 us; speedup 1.0000x reference)
//
#include <hip/hip_runtime.h>
#include <hip/hip_bf16.h>

// NaryTreeLSTM  B=32768, K=4, I=256, H=256
// DTYPE MODEL (verified round 3, PASS): inputs fp32, outputs fp32, bf16-scale
// threshold => bf16 MFMA pipeline, fp32 accum, fp32 out stores.
//
// ROUND-4 CHANGES (latency/occupancy attack, round-3 counters showed
// MfmaUtil 7%, Occ 27%/12%, WRITE amplification 170 vs 80 MB):
//  - cc layout [b][n][k] bf16: child stores bf16x4 dense, root loads bf16x4
//    dense (kills 2-byte scatter on both sides of the cc round-trip)
//  - root: wave=16 rows, block=64 rows, ct-split x4 -> 2048 blocks (was 256)
//  - child: ct-split x2 -> (1024,2) blocks (was 1024), 8 blocks/CU
//
// ws layout:
//   cc   [B][H][K] bf16   child cell states (k-innermost!)
//   hsum [B][H]    bf16   sum_k child hidden
//   bf16 weight copies: Wi,Wf,Wo,Wu (H*I), Ui,Uo,Uu (H*H), WfK (K*H*H)

#define BB 32768
#define KK 4
#define II 256
#define HH 256

typedef __bf16 bf16x8 __attribute__((ext_vector_type(8)));
typedef __bf16 bf16x4 __attribute__((ext_vector_type(4)));
typedef float f32x4 __attribute__((ext_vector_type(4)));

#define MFMA16(a, b, c) __builtin_amdgcn_mfma_f32_16x16x32_bf16(a, b, c, 0, 0, 0)

static __device__ __forceinline__ float fsig(float x) {
    return 1.0f / (1.0f + __expf(-x));
}
// tanh(x) = 1 - 2/(exp(2x)+1): saturates correctly at both extremes
static __device__ __forceinline__ float ftanhf(float x) {
    float e = __expf(2.0f * x);
    return 1.0f - 2.0f / (e + 1.0f);
}

static __device__ __forceinline__ bf16x8 cvt8(const float* __restrict__ p) {
    float4 f0 = ((const float4*)p)[0];
    float4 f1 = ((const float4*)p)[1];
    bf16x8 v;
    v[0] = (__bf16)f0.x; v[1] = (__bf16)f0.y; v[2] = (__bf16)f0.z; v[3] = (__bf16)f0.w;
    v[4] = (__bf16)f1.x; v[5] = (__bf16)f1.y; v[6] = (__bf16)f1.z; v[7] = (__bf16)f1.w;
    return v;
}

// ---------------- Kernel 0: fp32 -> bf16 weight conversion ----------------
struct CvtArgs {
    const float* src[8];
    __bf16* dst[8];
    int n[8];
};
__global__ __launch_bounds__(256) void cvt_k(CvtArgs a) {
    const int t = blockIdx.y;
    const int i = (blockIdx.x * 256 + threadIdx.x) * 4;
    if (i < a.n[t]) {
        float4 f = *(const float4*)(a.src[t] + i);
        bf16x4 v;
        v[0] = (__bf16)f.x; v[1] = (__bf16)f.y; v[2] = (__bf16)f.z; v[3] = (__bf16)f.w;
        *(bf16x4*)(a.dst[t] + i) = v;
    }
}

// ---------------- Kernel 1: child (leaf) gates ----------------
// Wave = 32 child rows (2 MFMA row-tiles) x 8 col-tiles (ct half from grid.y).
// D-layout (row=quad*4+r, col=lane&15): lane's 4 acc regs = 4 children of one
// b-row -> cc bf16x4 dense store + in-lane hsum reduction.
__global__ __launch_bounds__(256) void child_gates_k(
    const float* __restrict__ child_x,
    const __bf16* __restrict__ Wi, const __bf16* __restrict__ Wo,
    const __bf16* __restrict__ Wu,
    const float* __restrict__ bi, const float* __restrict__ bo,
    const float* __restrict__ bu,
    __bf16* __restrict__ cc, __bf16* __restrict__ hsum)
{
    const int lane = threadIdx.x & 63;
    const int wave = threadIdx.x >> 6;
    const int l16  = lane & 15;
    const int quad = lane >> 4;
    const int wbase = blockIdx.x * 128 + wave * 32;  // child-row base for wave
    const int ctbase = blockIdx.y * 8;               // col-tile range base

    // A[m=l16][k=quad*8+j], fp32 loads converted to bf16 fragments
    bf16x8 a[2][8];
#pragma unroll
    for (int t = 0; t < 2; ++t) {
        const float* rp = child_x + (size_t)(wbase + t * 16 + l16) * II + quad * 8;
#pragma unroll
        for (int ks = 0; ks < 8; ++ks)
            a[t][ks] = cvt8(rp + ks * 32);
    }

    for (int ctl = 0; ctl < 8; ++ctl) {
        const int n = (ctbase + ctl) * 16 + l16;
        const float bin = bi[n], bon = bo[n], bun = bu[n];
        const int wo = n * II + quad * 8;  // B[k][n] = W[n][k]: contiguous 16B
        f32x4 ai[2] = {{0.f,0.f,0.f,0.f},{0.f,0.f,0.f,0.f}};
        f32x4 ao[2] = {{0.f,0.f,0.f,0.f},{0.f,0.f,0.f,0.f}};
        f32x4 au[2] = {{0.f,0.f,0.f,0.f},{0.f,0.f,0.f,0.f}};
#pragma unroll
        for (int ks = 0; ks < 8; ++ks) {
            bf16x8 bwi = *(const bf16x8*)(Wi + wo + ks * 32);
            bf16x8 bwo = *(const bf16x8*)(Wo + wo + ks * 32);
            bf16x8 bwu = *(const bf16x8*)(Wu + wo + ks * 32);
#pragma unroll
            for (int t = 0; t < 2; ++t) {
                ai[t] = MFMA16(a[t][ks], bwi, ai[t]);
                ao[t] = MFMA16(a[t][ks], bwo, ao[t]);
                au[t] = MFMA16(a[t][ks], bwu, au[t]);
            }
        }
#pragma unroll
        for (int t = 0; t < 2; ++t) {
            const int b = (wbase >> 2) + t * 4 + quad;  // b-row; lane's 4 regs = k=0..3
            float chs = 0.f;
            bf16x4 ccv4;
#pragma unroll
            for (int r = 0; r < 4; ++r) {
                float civ = fsig(ai[t][r] + bin);
                float cov = fsig(ao[t][r] + bon);
                float cuv = ftanhf(au[t][r] + bun);
                float ccv = civ * cuv;
                chs += cov * ftanhf(ccv);
                ccv4[r] = (__bf16)ccv;
            }
            *(bf16x4*)(cc + ((size_t)b * HH + n) * KK) = ccv4;  // dense 8B/lane
            hsum[(size_t)b * HH + n] = (__bf16)chs;
        }
    }
}

// ---------------- Kernel 2: root (node) gates ----------------
// Wave = 16 b-rows x 4 col-tiles (quarter from grid.y). 2 passes (i/o/u, then
// f-family) to cap live VGPRs (~128 -> 4 waves/SIMD target).
__global__ __launch_bounds__(256) void root_k(
    const float* __restrict__ x,
    const __bf16* __restrict__ Wi, const __bf16* __restrict__ Wf,
    const __bf16* __restrict__ Wo, const __bf16* __restrict__ Wu,
    const __bf16* __restrict__ Ui, const __bf16* __restrict__ Uo,
    const __bf16* __restrict__ Uu, const __bf16* __restrict__ WfK,
    const float* __restrict__ bi, const float* __restrict__ bf_,
    const float* __restrict__ bo, const float* __restrict__ bu,
    const __bf16* __restrict__ cc, const __bf16* __restrict__ hsum,
    float* __restrict__ out)
{
    const int lane = threadIdx.x & 63;
    const int wave = threadIdx.x >> 6;
    const int l16  = lane & 15;
    const int quad = lane >> 4;
    const int rbase = blockIdx.x * 64 + wave * 16;  // b-row base of wave
    const int ctbase = blockIdx.y * 4;

    bf16x8 ax[8], ah[8];
    {
        const float*  xp = x    + (size_t)(rbase + l16) * II + quad * 8;
        const __bf16* hp = hsum + (size_t)(rbase + l16) * HH + quad * 8;
#pragma unroll
        for (int ks = 0; ks < 8; ++ks) {
            ax[ks] = cvt8(xp + ks * 32);
            ah[ks] = *(const bf16x8*)(hp + ks * 32);
        }
    }

    for (int ctl = 0; ctl < 4; ++ctl) {
        const int n = (ctbase + ctl) * 16 + l16;
        const float bin = bi[n], bfn = bf_[n], bon = bo[n], bun = bu[n];
        const int wo = n * II + quad * 8;

        // ---- pass 1: i, o, u ----
        f32x4 ai = {0.f,0.f,0.f,0.f};
        f32x4 ao = {0.f,0.f,0.f,0.f};
        f32x4 au = {0.f,0.f,0.f,0.f};
#pragma unroll
        for (int ks = 0; ks < 8; ++ks) {
            const int o = wo + ks * 32;
            ai = MFMA16(ax[ks], *(const bf16x8*)(Wi + o), ai);
            ai = MFMA16(ah[ks], *(const bf16x8*)(Ui + o), ai);
            ao = MFMA16(ax[ks], *(const bf16x8*)(Wo + o), ao);
            ao = MFMA16(ah[ks], *(const bf16x8*)(Uo + o), ao);
            au = MFMA16(ax[ks], *(const bf16x8*)(Wu + o), au);
            au = MFMA16(ah[ks], *(const bf16x8*)(Uu + o), au);
        }
        float iv[4], ov[4], uv[4];
#pragma unroll
        for (int r = 0; r < 4; ++r) {
            iv[r] = fsig(ai[r] + bin);
            ov[r] = fsig(ao[r] + bon);
            uv[r] = ftanhf(au[r] + bun);
        }

        // ---- pass 2: f-family ----
        f32x4 axf = {0.f,0.f,0.f,0.f};
        f32x4 af[4] = {{0.f,0.f,0.f,0.f},{0.f,0.f,0.f,0.f},
                       {0.f,0.f,0.f,0.f},{0.f,0.f,0.f,0.f}};
#pragma unroll
        for (int ks = 0; ks < 8; ++ks) {
            const int o = wo + ks * 32;
            axf   = MFMA16(ax[ks], *(const bf16x8*)(Wf + o), axf);
            af[0] = MFMA16(ah[ks], *(const bf16x8*)(WfK + 0 * HH * II + o), af[0]);
            af[1] = MFMA16(ah[ks], *(const bf16x8*)(WfK + 1 * HH * II + o), af[1]);
            af[2] = MFMA16(ah[ks], *(const bf16x8*)(WfK + 2 * HH * II + o), af[2]);
            af[3] = MFMA16(ah[ks], *(const bf16x8*)(WfK + 3 * HH * II + o), af[3]);
        }

        // ---- epilogue: dense bf16x4 cc loads, fp32 stores ----
#pragma unroll
        for (int r = 0; r < 4; ++r) {
            const int b = rbase + quad * 4 + r;
            bf16x4 cv4 = *(const bf16x4*)(cc + ((size_t)b * HH + n) * KK);
            const float xfv = axf[r] + bfn;
            float cv = iv[r] * uv[r];
#pragma unroll
            for (int k = 0; k < 4; ++k)
                cv += fsig(xfv + af[k][r]) * (float)cv4[k];
            float hv = ov[r] * ftanhf(cv);
            out[(size_t)b * HH + n] = hv;                    // h
            out[(size_t)BB * HH + (size_t)b * HH + n] = cv;  // c
        }
    }
}

extern "C" void kernel_launch(void* const* d_in, const int* in_sizes, int n_in,
                              void* d_out, int out_size, void* d_ws, size_t ws_size,
                              hipStream_t stream) {
    const float* x    = (const float*)d_in[0];
    const float* cx   = (const float*)d_in[1];
    const float* Wi   = (const float*)d_in[2];
    const float* bi   = (const float*)d_in[3];
    const float* Wf   = (const float*)d_in[4];
    const float* bf_  = (const float*)d_in[5];
    const float* Wo   = (const float*)d_in[6];
    const float* bo   = (const float*)d_in[7];
    const float* Wu   = (const float*)d_in[8];
    const float* bu   = (const float*)d_in[9];
    const float* Ui   = (const float*)d_in[10];
    const float* Uo   = (const float*)d_in[11];
    const float* Uu   = (const float*)d_in[12];
    const float* WfK  = (const float*)d_in[13];

    __bf16* cc = (__bf16*)d_ws;                     // [B][H][K]
    __bf16* hs = cc + (size_t)BB * KK * HH;         // [B][H]
    __bf16* wb = hs + (size_t)BB * HH;              // bf16 weight block
    __bf16 *Wi_b = wb,            *Wf_b = Wi_b + HH * II, *Wo_b = Wf_b + HH * II,
           *Wu_b = Wo_b + HH * II, *Ui_b = Wu_b + HH * II, *Uo_b = Ui_b + HH * HH,
           *Uu_b = Uo_b + HH * HH, *WfK_b = Uu_b + HH * HH;  // WfK: K*H*H

    CvtArgs ca;
    ca.src[0] = Wi;  ca.dst[0] = Wi_b;  ca.n[0] = HH * II;
    ca.src[1] = Wf;  ca.dst[1] = Wf_b;  ca.n[1] = HH * II;
    ca.src[2] = Wo;  ca.dst[2] = Wo_b;  ca.n[2] = HH * II;
    ca.src[3] = Wu;  ca.dst[3] = Wu_b;  ca.n[3] = HH * II;
    ca.src[4] = Ui;  ca.dst[4] = Ui_b;  ca.n[4] = HH * HH;
    ca.src[5] = Uo;  ca.dst[5] = Uo_b;  ca.n[5] = HH * HH;
    ca.src[6] = Uu;  ca.dst[6] = Uu_b;  ca.n[6] = HH * HH;
    ca.src[7] = WfK; ca.dst[7] = WfK_b; ca.n[7] = KK * HH * HH;

    cvt_k<<<dim3(KK * HH * HH / 1024, 8), dim3(256), 0, stream>>>(ca);
    child_gates_k<<<dim3(BB * KK / 128, 2), dim3(256), 0, stream>>>(
        cx, Wi_b, Wo_b, Wu_b, bi, bo, bu, cc, hs);
    root_k<<<dim3(BB / 64, 4), dim3(256), 0, stream>>>(
        x, Wi_b, Wf_b, Wo_b, Wu_b, Ui_b, Uo_b, Uu_b, WfK_b,
        bi, bf_, bo, bu, cc, hs, (float*)d_out);
}

// Round 5
// 602.387 us; speedup vs baseline: 1.4268x; 1.4268x over previous
//
#include <hip/hip_runtime.h>
#include <hip/hip_bf16.h>

// NaryTreeLSTM  B=32768, K=4, I=256, H=256
// DTYPE MODEL (verified): inputs fp32, outputs fp32, bf16-scale threshold
// => bf16 MFMA pipeline, fp32 accum, fp32 out stores.
//
// ROUND-5: child rebuilt as "weights-in-registers, A-streamed-through-LDS":
//   block = 512 thr = 8 waves; wave w owns ct = (blockIdx.x&1)*8 + w and holds
//   Wi/Wo/Wu ct-slices in 96 VGPRs for the whole kernel. Block streams 16
//   row-tiles (16 child rows each) through double-buffered LDS (fp32->bf16
//   cvt at stage time). One barrier/tile; t+1 global loads issue under
//   compute of t. Weight gathers: once per block (was: once per ct per wave).
// root: round-3 2-tile shape (better MFMA:load) + dense cc + ct-split x2 +
//   __launch_bounds__(256,2) for a 256-VGPR load-pipelining budget.
//
// ws: cc [B][H][K] bf16, hsum [B][H] bf16, bf16 weight copies.

#define BB 32768
#define KK 4
#define II 256
#define HH 256

typedef __bf16 bf16x8 __attribute__((ext_vector_type(8)));
typedef __bf16 bf16x4 __attribute__((ext_vector_type(4)));
typedef float f32x4 __attribute__((ext_vector_type(4)));

#define MFMA16(a, b, c) __builtin_amdgcn_mfma_f32_16x16x32_bf16(a, b, c, 0, 0, 0)

static __device__ __forceinline__ float fsig(float x) {
    return 1.0f / (1.0f + __expf(-x));
}
static __device__ __forceinline__ float ftanhf(float x) {
    float e = __expf(2.0f * x);
    return 1.0f - 2.0f / (e + 1.0f);
}

static __device__ __forceinline__ bf16x8 cvt8v(float4 f0, float4 f1) {
    bf16x8 v;
    v[0] = (__bf16)f0.x; v[1] = (__bf16)f0.y; v[2] = (__bf16)f0.z; v[3] = (__bf16)f0.w;
    v[4] = (__bf16)f1.x; v[5] = (__bf16)f1.y; v[6] = (__bf16)f1.z; v[7] = (__bf16)f1.w;
    return v;
}
static __device__ __forceinline__ bf16x8 cvt8(const float* __restrict__ p) {
    return cvt8v(((const float4*)p)[0], ((const float4*)p)[1]);
}

// ---------------- Kernel 0: fp32 -> bf16 weight conversion ----------------
struct CvtArgs {
    const float* src[8];
    __bf16* dst[8];
    int n[8];
};
__global__ __launch_bounds__(256) void cvt_k(CvtArgs a) {
    const int t = blockIdx.y;
    const int i = (blockIdx.x * 256 + threadIdx.x) * 4;
    if (i < a.n[t]) {
        float4 f = *(const float4*)(a.src[t] + i);
        bf16x4 v;
        v[0] = (__bf16)f.x; v[1] = (__bf16)f.y; v[2] = (__bf16)f.z; v[3] = (__bf16)f.w;
        *(bf16x4*)(a.dst[t] + i) = v;
    }
}

// ---------------- Kernel 1: child gates, streaming ----------------
// grid.x = 1024 linear: rowchunk = bid>>1 (256 child rows), cthalf = bid&1.
// LDS row stride 264 elems (528 B): 16B-superbank stride 33 -> uniform
// 8-lane/superbank for both ds_write (staging) and ds_read_b128 (frags).
#define ROWSTR 264
__global__ __launch_bounds__(512, 2) void child_gates_k(
    const float* __restrict__ child_x,
    const __bf16* __restrict__ Wi, const __bf16* __restrict__ Wo,
    const __bf16* __restrict__ Wu,
    const float* __restrict__ bi, const float* __restrict__ bo,
    const float* __restrict__ bu,
    __bf16* __restrict__ cc, __bf16* __restrict__ hsum)
{
    const int tid  = threadIdx.x;
    const int wave = tid >> 6;
    const int lane = tid & 63;
    const int l16  = lane & 15;
    const int quad = lane >> 4;
    const int rowchunk = blockIdx.x >> 1;           // 256 child rows each
    const int ct   = (blockIdx.x & 1) * 8 + wave;   // this wave's col-tile
    const int n    = ct * 16 + l16;

    // --- weight fragments for this ct, held for the whole kernel (96 VGPR)
    bf16x8 w[3][8];
    {
        const int base = n * II + quad * 8;
#pragma unroll
        for (int ks = 0; ks < 8; ++ks) {
            w[0][ks] = *(const bf16x8*)(Wi + base + ks * 32);
            w[1][ks] = *(const bf16x8*)(Wo + base + ks * 32);
            w[2][ks] = *(const bf16x8*)(Wu + base + ks * 32);
        }
    }
    const float bin = bi[n], bon = bo[n], bun = bu[n];

    __shared__ __bf16 As[2][16 * ROWSTR];

    // staging map: 512 thr, thread -> (row = tid>>5, col8 = (tid&31)*8)
    const int srow = tid >> 5;
    const int scol = (tid & 31) * 8;
    const float* gbase = child_x + ((size_t)rowchunk * 256 + srow) * II + scol;

    float4 f0 = ((const float4*)gbase)[0];
    float4 f1 = ((const float4*)gbase)[1];
    *(bf16x8*)(&As[0][srow * ROWSTR + scol]) = cvt8v(f0, f1);
    __syncthreads();

    for (int t = 0; t < 16; ++t) {
        float4 g0, g1;
        if (t < 15) {   // issue t+1 global loads now; consume after compute
            const float* gp = gbase + (size_t)(t + 1) * 16 * II;
            g0 = ((const float4*)gp)[0];
            g1 = ((const float4*)gp)[1];
        }

        // --- compute tile t from LDS
        const __bf16* ap = &As[t & 1][l16 * ROWSTR + quad * 8];
        f32x4 ai = {0.f,0.f,0.f,0.f}, ao = {0.f,0.f,0.f,0.f}, au = {0.f,0.f,0.f,0.f};
#pragma unroll
        for (int ks = 0; ks < 8; ++ks) {
            bf16x8 a = *(const bf16x8*)(ap + ks * 32);
            ai = MFMA16(a, w[0][ks], ai);
            ao = MFMA16(a, w[1][ks], ao);
            au = MFMA16(a, w[2][ks], au);
        }

        // --- epilogue: lane's 4 regs = 4 children of b = rowchunk*64+t*4+quad
        {
            const int b = rowchunk * 64 + t * 4 + quad;
            float chs = 0.f;
            bf16x4 ccv4;
#pragma unroll
            for (int r = 0; r < 4; ++r) {
                float civ = fsig(ai[r] + bin);
                float cov = fsig(ao[r] + bon);
                float cuv = ftanhf(au[r] + bun);
                float ccv = civ * cuv;
                chs += cov * ftanhf(ccv);
                ccv4[r] = (__bf16)ccv;
            }
            *(bf16x4*)(cc + ((size_t)b * HH + n) * KK) = ccv4;
            hsum[(size_t)b * HH + n] = (__bf16)chs;
        }

        if (t < 15)
            *(bf16x8*)(&As[(t + 1) & 1][srow * ROWSTR + scol]) = cvt8v(g0, g1);
        __syncthreads();
    }
}

// ---------------- Kernel 2: root gates ----------------
// 2 row-tiles/wave (32 rows), 8 cts per wave (grid.y=2 halves),
// launch_bounds(256,2): 256-VGPR budget for deep load pipelining.
__global__ __launch_bounds__(256, 2) void root_k(
    const float* __restrict__ x,
    const __bf16* __restrict__ Wi, const __bf16* __restrict__ Wf,
    const __bf16* __restrict__ Wo, const __bf16* __restrict__ Wu,
    const __bf16* __restrict__ Ui, const __bf16* __restrict__ Uo,
    const __bf16* __restrict__ Uu, const __bf16* __restrict__ WfK,
    const float* __restrict__ bi, const float* __restrict__ bf_,
    const float* __restrict__ bo, const float* __restrict__ bu,
    const __bf16* __restrict__ cc, const __bf16* __restrict__ hsum,
    float* __restrict__ out)
{
    const int lane = threadIdx.x & 63;
    const int wave = threadIdx.x >> 6;
    const int l16  = lane & 15;
    const int quad = lane >> 4;
    const int rbase = blockIdx.x * 128 + wave * 32;  // b-row base of wave
    const int ctbase = blockIdx.y * 8;

    bf16x8 ax[2][8], ah[2][8];
#pragma unroll
    for (int t = 0; t < 2; ++t) {
        const float*  xp = x    + (size_t)(rbase + t * 16 + l16) * II + quad * 8;
        const __bf16* hp = hsum + (size_t)(rbase + t * 16 + l16) * HH + quad * 8;
#pragma unroll
        for (int ks = 0; ks < 8; ++ks) {
            ax[t][ks] = cvt8(xp + ks * 32);
            ah[t][ks] = *(const bf16x8*)(hp + ks * 32);
        }
    }

    for (int ctl = 0; ctl < 8; ++ctl) {
        const int n = (ctbase + ctl) * 16 + l16;
        const float bin = bi[n], bfn = bf_[n], bon = bo[n], bun = bu[n];
        const int wo = n * II + quad * 8;

        // ---- pass 1: i, o, u ----
        f32x4 ai[2] = {{0.f,0.f,0.f,0.f},{0.f,0.f,0.f,0.f}};
        f32x4 ao[2] = {{0.f,0.f,0.f,0.f},{0.f,0.f,0.f,0.f}};
        f32x4 au[2] = {{0.f,0.f,0.f,0.f},{0.f,0.f,0.f,0.f}};
#pragma unroll
        for (int ks = 0; ks < 8; ++ks) {
            const int o = wo + ks * 32;
            bf16x8 bwi = *(const bf16x8*)(Wi + o);
            bf16x8 bui = *(const bf16x8*)(Ui + o);
            bf16x8 bwo = *(const bf16x8*)(Wo + o);
            bf16x8 buo = *(const bf16x8*)(Uo + o);
            bf16x8 bwu = *(const bf16x8*)(Wu + o);
            bf16x8 buu = *(const bf16x8*)(Uu + o);
#pragma unroll
            for (int t = 0; t < 2; ++t) {
                ai[t] = MFMA16(ax[t][ks], bwi, ai[t]);
                ai[t] = MFMA16(ah[t][ks], bui, ai[t]);
                ao[t] = MFMA16(ax[t][ks], bwo, ao[t]);
                ao[t] = MFMA16(ah[t][ks], buo, ao[t]);
                au[t] = MFMA16(ax[t][ks], bwu, au[t]);
                au[t] = MFMA16(ah[t][ks], buu, au[t]);
            }
        }
        float iv[2][4], ov[2][4], uv[2][4];
#pragma unroll
        for (int t = 0; t < 2; ++t)
#pragma unroll
            for (int r = 0; r < 4; ++r) {
                iv[t][r] = fsig(ai[t][r] + bin);
                ov[t][r] = fsig(ao[t][r] + bon);
                uv[t][r] = ftanhf(au[t][r] + bun);
            }

        // ---- pass 2: f-family ----
        f32x4 axf[2] = {{0.f,0.f,0.f,0.f},{0.f,0.f,0.f,0.f}};
        f32x4 af[4][2] = {{{0.f,0.f,0.f,0.f},{0.f,0.f,0.f,0.f}},
                          {{0.f,0.f,0.f,0.f},{0.f,0.f,0.f,0.f}},
                          {{0.f,0.f,0.f,0.f},{0.f,0.f,0.f,0.f}},
                          {{0.f,0.f,0.f,0.f},{0.f,0.f,0.f,0.f}}};
#pragma unroll
        for (int ks = 0; ks < 8; ++ks) {
            const int o = wo + ks * 32;
            bf16x8 bwf = *(const bf16x8*)(Wf + o);
            bf16x8 bk0 = *(const bf16x8*)(WfK + 0 * HH * II + o);
            bf16x8 bk1 = *(const bf16x8*)(WfK + 1 * HH * II + o);
            bf16x8 bk2 = *(const bf16x8*)(WfK + 2 * HH * II + o);
            bf16x8 bk3 = *(const bf16x8*)(WfK + 3 * HH * II + o);
#pragma unroll
            for (int t = 0; t < 2; ++t) {
                axf[t]   = MFMA16(ax[t][ks], bwf, axf[t]);
                af[0][t] = MFMA16(ah[t][ks], bk0, af[0][t]);
                af[1][t] = MFMA16(ah[t][ks], bk1, af[1][t]);
                af[2][t] = MFMA16(ah[t][ks], bk2, af[2][t]);
                af[3][t] = MFMA16(ah[t][ks], bk3, af[3][t]);
            }
        }

        // ---- epilogue: dense bf16x4 cc loads, fp32 stores ----
#pragma unroll
        for (int t = 0; t < 2; ++t)
#pragma unroll
            for (int r = 0; r < 4; ++r) {
                const int b = rbase + t * 16 + quad * 4 + r;
                bf16x4 cv4 = *(const bf16x4*)(cc + ((size_t)b * HH + n) * KK);
                const float xfv = axf[t][r] + bfn;
                float cv = iv[t][r] * uv[t][r];
#pragma unroll
                for (int k = 0; k < 4; ++k)
                    cv += fsig(xfv + af[k][t][r]) * (float)cv4[k];
                float hv = ov[t][r] * ftanhf(cv);
                out[(size_t)b * HH + n] = hv;                    // h
                out[(size_t)BB * HH + (size_t)b * HH + n] = cv;  // c
            }
    }
}

extern "C" void kernel_launch(void* const* d_in, const int* in_sizes, int n_in,
                              void* d_out, int out_size, void* d_ws, size_t ws_size,
                              hipStream_t stream) {
    const float* x    = (const float*)d_in[0];
    const float* cx   = (const float*)d_in[1];
    const float* Wi   = (const float*)d_in[2];
    const float* bi   = (const float*)d_in[3];
    const float* Wf   = (const float*)d_in[4];
    const float* bf_  = (const float*)d_in[5];
    const float* Wo   = (const float*)d_in[6];
    const float* bo   = (const float*)d_in[7];
    const float* Wu   = (const float*)d_in[8];
    const float* bu   = (const float*)d_in[9];
    const float* Ui   = (const float*)d_in[10];
    const float* Uo   = (const float*)d_in[11];
    const float* Uu   = (const float*)d_in[12];
    const float* WfK  = (const float*)d_in[13];

    __bf16* cc = (__bf16*)d_ws;                     // [B][H][K]
    __bf16* hs = cc + (size_t)BB * KK * HH;         // [B][H]
    __bf16* wb = hs + (size_t)BB * HH;              // bf16 weight block
    __bf16 *Wi_b = wb,            *Wf_b = Wi_b + HH * II, *Wo_b = Wf_b + HH * II,
           *Wu_b = Wo_b + HH * II, *Ui_b = Wu_b + HH * II, *Uo_b = Ui_b + HH * HH,
           *Uu_b = Uo_b + HH * HH, *WfK_b = Uu_b + HH * HH;  // WfK: K*H*H

    CvtArgs ca;
    ca.src[0] = Wi;  ca.dst[0] = Wi_b;  ca.n[0] = HH * II;
    ca.src[1] = Wf;  ca.dst[1] = Wf_b;  ca.n[1] = HH * II;
    ca.src[2] = Wo;  ca.dst[2] = Wo_b;  ca.n[2] = HH * II;
    ca.src[3] = Wu;  ca.dst[3] = Wu_b;  ca.n[3] = HH * II;
    ca.src[4] = Ui;  ca.dst[4] = Ui_b;  ca.n[4] = HH * HH;
    ca.src[5] = Uo;  ca.dst[5] = Uo_b;  ca.n[5] = HH * HH;
    ca.src[6] = Uu;  ca.dst[6] = Uu_b;  ca.n[6] = HH * HH;
    ca.src[7] = WfK; ca.dst[7] = WfK_b; ca.n[7] = KK * HH * HH;

    cvt_k<<<dim3(KK * HH * HH / 1024, 8), dim3(256), 0, stream>>>(ca);
    child_gates_k<<<dim3(1024), dim3(512), 0, stream>>>(
        cx, Wi_b, Wo_b, Wu_b, bi, bo, bu, cc, hs);
    root_k<<<dim3(BB / 128, 2), dim3(256), 0, stream>>>(
        x, Wi_b, Wf_b, Wo_b, Wu_b, Ui_b, Uo_b, Uu_b, WfK_b,
        bi, bf_, bo, bu, cc, hs, (float*)d_out);
}